// Round 12
// baseline (520.594 us; speedup 1.0000x reference)
//
#include <hip/hip_runtime.h>
#include <hip/hip_bf16.h>

typedef __attribute__((ext_vector_type(8))) short short8;
typedef __attribute__((ext_vector_type(4))) float f32x4;

constexpr int S_DIM   = 1024;
constexpr int IN_DIM  = 4096;   // K
constexpr int OUT_DIM = 4096;   // N
constexpr int NLORA   = 8;

typedef __attribute__((address_space(3))) unsigned char lds_byte_t;
typedef const __attribute__((address_space(1))) unsigned char glb_byte_t;

__device__ __forceinline__ unsigned short f2bf(float a) {
    union { __hip_bfloat16 h; unsigned short u; } c;
    c.h = __float2bfloat16(a);
    return c.u;
}
__device__ __forceinline__ unsigned int bf2pk(float a, float b) {
    return (unsigned int)f2bf(a) | ((unsigned int)f2bf(b) << 16);
}

// ---- prep: w[a][k][n] fp32 -> wt[a][n][k] bf16, only USED adapters ----------
constexpr int WBLKS = NLORA * 64 * 64;   // 32768

__global__ __launch_bounds__(256)
void prep_w(const float* __restrict__ w, unsigned short* __restrict__ wt,
            const int* __restrict__ aids, int nb) {
    const int bid = blockIdx.x;
    const int tid = threadIdx.x;

    const int a = bid >> 12;
    bool used = false;
    for (int i = 0; i < nb; ++i) used |= (aids[i] == a);
    if (!used) return;

    const int r  = bid & 4095;
    const int n0 = (r & 63) * 64;
    const int k0 = (r >> 6) * 64;

    __shared__ __align__(16) unsigned short t[64][72];
    const float* wb = w + (size_t)a * IN_DIM * OUT_DIM;

    const int nl = (tid & 15) * 4;
    #pragma unroll
    for (int p = 0; p < 4; ++p) {
        const int kl = p * 16 + (tid >> 4);
        f32x4 v = *reinterpret_cast<const f32x4*>(wb + (size_t)(k0 + kl) * OUT_DIM + n0 + nl);
        t[nl + 0][kl] = f2bf(v[0]);
        t[nl + 1][kl] = f2bf(v[1]);
        t[nl + 2][kl] = f2bf(v[2]);
        t[nl + 3][kl] = f2bf(v[3]);
    }
    __syncthreads();
    unsigned short* wtb = wt + (size_t)a * IN_DIM * OUT_DIM;
    const int chunk = tid & 7;
    #pragma unroll
    for (int q = 0; q < 2; ++q) {
        const int row = q * 32 + (tid >> 3);
        uint4 d = *reinterpret_cast<const uint4*>(&t[row][chunk * 8]);
        *reinterpret_cast<uint4*>(wtb + (size_t)(n0 + row) * IN_DIM + k0 + chunk * 8) = d;
    }
}

// ---- main GEMM: 256x256, 4 phases/K-tile; A fused from x fp32 (reg-staged
// swizzled ds_write), B via global_load_lds from bf16 wt ----------------------
constexpr int BM = 256;
constexpr int BN = 256;
constexpr int BK = 64;
constexpr int NT = IN_DIM / BK;   // 64

__global__ __launch_bounds__(512, 2)
void gemm8p(const float* __restrict__ x, const unsigned short* __restrict__ wt,
            const int* __restrict__ aids, float* __restrict__ out) {
    __shared__ __align__(16) unsigned char lds[2][65536];

    // T1 XCD swizzle: 512 wgs, 64/XCD = exactly one batch per XCD
    const int bid = blockIdx.x;
    const int swz = (bid & 7) * 64 + (bid >> 3);
    const int bz  = swz >> 6;
    const int rem = swz & 63;
    const int by  = rem >> 4;
    const int bx  = rem & 15;

    const int tid  = threadIdx.x;
    const int lane = tid & 63;
    const int wid  = tid >> 6;
    const int bm0  = by * BM;
    const int bn0  = bx * BN;
    const int aid  = aids[bz];

    const float* Ax = x + ((size_t)bz * S_DIM + bm0) * IN_DIM;
    const unsigned short* Bb = wt + (size_t)aid * IN_DIM * OUT_DIM + (size_t)bn0 * IN_DIM;

    const int wr  = (wid >> 2) * 128;
    const int wc  = (wid & 3) * 64;
    const int l15 = lane & 15;
    const int lk  = lane >> 4;
    const int rl  = lane >> 3;
    const int l7  = lane & 7;
    const int ksrcB = (l7 ^ rl) << 3;   // B gload_lds source pre-swizzle (proven)

    f32x4 acc[8][4] = {};

    // B group g (g=np): rows {w*64+g*32..+31} = chunks (wid>>1)*8+g*4+(wid&1)*2+c
    // == exactly the rows ALL waves read at readB(np=g)  [proven r10/r11]
    auto stageB = [&](int buf, int k0, int g) {
        #pragma unroll
        for (int c = 0; c < 2; ++c) {
            const int chunk = (wid >> 1) * 8 + g * 4 + (wid & 1) * 2 + c;
            const int row   = chunk * 8 + rl;
            __builtin_amdgcn_global_load_lds(
                (glb_byte_t*)(Bb + (size_t)row * IN_DIM + k0 + ksrcB),
                (lds_byte_t*)(&lds[buf][32768 + chunk * 1024]), 16, 0, 0);
        }
    };

    // A fused staging: half g covers chunks {c*16+g*8+wid} = rows {g*64..+63} u
    // {128+g*64..+63} == rows all waves read at readA(mh=g). Thread loads its
    // 8-elem k-slice (l7*8) of each row as fp32, cvt_pk, one swizzled b128 write.
    auto issueXA = [&](int k0, int g, f32x4 (&v)[4]) {
        #pragma unroll
        for (int c = 0; c < 2; ++c) {
            const int chunk = c * 16 + g * 8 + wid;
            const int row   = chunk * 8 + rl;
            const float* p = Ax + (size_t)row * IN_DIM + k0 + l7 * 8;
            v[c * 2 + 0] = *reinterpret_cast<const f32x4*>(p);
            v[c * 2 + 1] = *reinterpret_cast<const f32x4*>(p + 4);
        }
    };
    auto writeXA = [&](int buf, int g, f32x4 (&v)[4]) {
        #pragma unroll
        for (int c = 0; c < 2; ++c) {
            const int chunk = c * 16 + g * 8 + wid;
            uint4 d;
            d.x = bf2pk(v[c * 2][0], v[c * 2][1]);
            d.y = bf2pk(v[c * 2][2], v[c * 2][3]);
            d.z = bf2pk(v[c * 2 + 1][0], v[c * 2 + 1][1]);
            d.w = bf2pk(v[c * 2 + 1][2], v[c * 2 + 1][3]);
            // byte = row*128 + ((l7*16) ^ ((row&7)*16)); row&7 == rl
            const int off = chunk * 1024 + rl * 128 + (((l7 ^ rl)) << 4);
            *reinterpret_cast<uint4*>(&lds[buf][off]) = d;
        }
    };

    auto readA = [&](int buf, int mh, short8 (&af)[4][2]) {
        #pragma unroll
        for (int i = 0; i < 4; ++i) {
            const int row = wr + mh * 64 + i * 16 + l15;
            #pragma unroll
            for (int kc = 0; kc < 2; ++kc) {
                const int kb = kc * 64 + lk * 16;
                af[i][kc] = *reinterpret_cast<const short8*>(
                    &lds[buf][row * 128 + (kb ^ ((row & 7) << 4))]);
            }
        }
    };
    auto readB = [&](int buf, int np, short8 (&bf)[2][2]) {
        #pragma unroll
        for (int nn = 0; nn < 2; ++nn) {
            const int row = wc + np * 32 + nn * 16 + l15;
            #pragma unroll
            for (int kc = 0; kc < 2; ++kc) {
                const int kb = kc * 64 + lk * 16;
                bf[nn][kc] = *reinterpret_cast<const short8*>(
                    &lds[buf][32768 + row * 128 + (kb ^ ((row & 7) << 4))]);
            }
        }
    };

    auto qmfma = [&](short8 (&af)[4][2], short8 (&bf)[2][2], int mh, int np) {
        __builtin_amdgcn_s_setprio(1);
        #pragma unroll
        for (int i = 0; i < 4; ++i)
            #pragma unroll
            for (int nn = 0; nn < 2; ++nn)
                #pragma unroll
                for (int kc = 0; kc < 2; ++kc)
                    acc[mh * 4 + i][np * 2 + nn] = __builtin_amdgcn_mfma_f32_16x16x32_bf16(
                        af[i][kc], bf[nn][kc], acc[mh * 4 + i][np * 2 + nn], 0, 0, 0);
        __builtin_amdgcn_s_setprio(0);
    };

    f32x4 xa0[4], xa1[4];

    // prologue: A(t0) regs -> lds[0]; B(t0); A(t1) -> lds[1]; B(t1).
    // writeXA(t1)'s reg-dep drains B(t0); B(t1) drained by ph1(0)'s writeXA.
    issueXA(0, 0, xa0); issueXA(0, 1, xa1);
    __builtin_amdgcn_sched_barrier(0);
    stageB(0, 0, 0); stageB(0, 0, 1);
    __builtin_amdgcn_sched_barrier(0);
    writeXA(0, 0, xa0); writeXA(0, 1, xa1);
    issueXA(BK, 0, xa0); issueXA(BK, 1, xa1);
    __builtin_amdgcn_sched_barrier(0);
    stageB(1, BK, 0); stageB(1, BK, 1);
    __builtin_amdgcn_sched_barrier(0);
    writeXA(1, 0, xa0); writeXA(1, 1, xa1);
    asm volatile("s_waitcnt lgkmcnt(0)" ::: "memory");
    __builtin_amdgcn_sched_barrier(0);
    __builtin_amdgcn_s_barrier();

    short8 a0[4][2], a1[4][2], b0[2][2], b1[2][2];

    #pragma unroll 1
    for (int j = 0; j < NT; ++j) {
        const int rb = j & 1;                 // read buf; tile j+2 lands here too
        const int k2 = (j + 2) * BK;
        const bool pre = (j < NT - 2);

        // ---- ph0: (mh0,np0); issue A-regs for tile j+2 ----
        readA(rb, 0, a0);
        readB(rb, 0, b0);
        if (pre) issueXA(k2, 0, xa0);
        __builtin_amdgcn_sched_barrier(0);
        __builtin_amdgcn_s_barrier();
        qmfma(a0, b0, 0, 0);
        __builtin_amdgcn_s_barrier();

        // ---- ph1: (mh0,np1); write A-g0 (rows retired at ph0-end), issue xa1 ----
        readB(rb, 1, b1);
        if (pre) { writeXA(rb, 0, xa0); issueXA(k2, 1, xa1); }
        asm volatile("s_waitcnt lgkmcnt(0)" ::: "memory");
        __builtin_amdgcn_sched_barrier(0);
        __builtin_amdgcn_s_barrier();
        qmfma(a0, b1, 0, 1);
        __builtin_amdgcn_s_barrier();

        // ---- ph2: (mh1,np1); stage B-np0 (rows retired at ph0-end) ----
        readA(rb, 1, a1);
        if (pre) stageB(rb, k2, 0);
        __builtin_amdgcn_sched_barrier(0);
        __builtin_amdgcn_s_barrier();
        qmfma(a1, b1, 1, 1);
        __builtin_amdgcn_s_barrier();

        // ---- ph3: write A-g1 (retired ph2-end) + stage B-np1 (retired ph1-end) ----
        if (pre) {
            writeXA(rb, 1, xa1);
            stageB(rb, k2, 1);
        } else if (j == NT - 2) {
            asm volatile("s_waitcnt vmcnt(0)" ::: "memory");  // drain B(NT-1)
        }
        asm volatile("s_waitcnt lgkmcnt(0)" ::: "memory");
        __builtin_amdgcn_sched_barrier(0);
        __builtin_amdgcn_s_barrier();
        qmfma(a1, b0, 1, 0);
        __builtin_amdgcn_s_barrier();
    }

    // ---- epilogue: D layout col=lane&15, row=(lane>>4)*4+reg ----
    float* obase = out + ((size_t)bz * S_DIM + bm0 + wr) * OUT_DIM + bn0 + wc;
    #pragma unroll
    for (int m = 0; m < 8; ++m) {
        #pragma unroll
        for (int n = 0; n < 4; ++n) {
            const int col = n * 16 + l15;
            #pragma unroll
            for (int r = 0; r < 4; ++r) {
                obase[(size_t)(m * 16 + lk * 4 + r) * OUT_DIM + col] = acc[m][n][r];
            }
        }
    }
}

// ---- fallback: round-2 fused kernel (passes @1316us, needs no ws) -----------
constexpr int TMf = 128, TNf = 128, TKf = 64;
__global__ __launch_bounds__(256, 2)
void mlora_gemm(const float* __restrict__ x, const int* __restrict__ aids,
                const float* __restrict__ w, float* __restrict__ out) {
    __shared__ __align__(16) unsigned char Asf[TMf * TKf * 2];
    __shared__ __align__(16) unsigned char Bsf[TNf * TKf * 2];

    const int tid  = threadIdx.x;
    const int lane = tid & 63;
    const int wid  = tid >> 6;
    const int bn0  = blockIdx.x * TNf;
    const int bm0  = blockIdx.y * TMf;
    const int bb   = blockIdx.z;
    const int aid  = aids[bb];

    const float* Abase = x + ((size_t)bb * S_DIM + bm0) * IN_DIM;
    const float* Bbase = w + (size_t)aid * IN_DIM * OUT_DIM + bn0;

    const int wr = (wid >> 1) * 64;
    const int wc = (wid & 1) * 64;

    f32x4 acc[4][4] = {};

    const int a_row4 = tid >> 4;
    const int a_k    = (tid & 15) * 4;
    const int b_n  = tid & 127;
    const int b_k0 = (tid >> 7) * 8;
    const int l15 = lane & 15;
    const int lk  = lane >> 4;

    for (int k0 = 0; k0 < IN_DIM; k0 += TKf) {
        #pragma unroll
        for (int p = 0; p < 8; ++p) {
            const int row = p * 16 + a_row4;
            f32x4 v = *reinterpret_cast<const f32x4*>(Abase + (size_t)row * IN_DIM + (k0 + a_k));
            uint2 d;
            d.x = bf2pk(v[0], v[1]);
            d.y = bf2pk(v[2], v[3]);
            const int off = row * (TKf * 2) + ((a_k * 2) ^ ((row & 7) << 4));
            *reinterpret_cast<uint2*>(&Asf[off]) = d;
        }
        {
            const float* bp = Bbase + (size_t)(k0 + b_k0) * OUT_DIM + b_n;
            #pragma unroll
            for (int g = 0; g < 4; ++g) {
                float f0 = bp[(size_t)(g * 16 + 0) * OUT_DIM];
                float f1 = bp[(size_t)(g * 16 + 1) * OUT_DIM];
                float f2 = bp[(size_t)(g * 16 + 2) * OUT_DIM];
                float f3 = bp[(size_t)(g * 16 + 3) * OUT_DIM];
                float f4 = bp[(size_t)(g * 16 + 4) * OUT_DIM];
                float f5 = bp[(size_t)(g * 16 + 5) * OUT_DIM];
                float f6 = bp[(size_t)(g * 16 + 6) * OUT_DIM];
                float f7 = bp[(size_t)(g * 16 + 7) * OUT_DIM];
                uint4 d;
                d.x = bf2pk(f0, f1);
                d.y = bf2pk(f2, f3);
                d.z = bf2pk(f4, f5);
                d.w = bf2pk(f6, f7);
                const int ks = b_k0 + g * 16;
                const int off = b_n * (TKf * 2) + ((ks * 2) ^ ((b_n & 7) << 4));
                *reinterpret_cast<uint4*>(&Bsf[off]) = d;
            }
        }
        __syncthreads();
        #pragma unroll
        for (int kc = 0; kc < 2; ++kc) {
            const int kbyte = kc * 64 + lk * 16;
            short8 af[4], bfr[4];
            #pragma unroll
            for (int m = 0; m < 4; ++m) {
                const int row = wr + m * 16 + l15;
                af[m] = *reinterpret_cast<const short8*>(&Asf[row * (TKf * 2) + (kbyte ^ ((row & 7) << 4))]);
            }
            #pragma unroll
            for (int n = 0; n < 4; ++n) {
                const int row = wc + n * 16 + l15;
                bfr[n] = *reinterpret_cast<const short8*>(&Bsf[row * (TKf * 2) + (kbyte ^ ((row & 7) << 4))]);
            }
            #pragma unroll
            for (int m = 0; m < 4; ++m) {
                #pragma unroll
                for (int n = 0; n < 4; ++n) {
                    acc[m][n] = __builtin_amdgcn_mfma_f32_16x16x32_bf16(af[m], bfr[n], acc[m][n], 0, 0, 0);
                }
            }
        }
        __syncthreads();
    }

    float* obase = out + ((size_t)bb * S_DIM + bm0 + wr) * OUT_DIM + bn0 + wc;
    #pragma unroll
    for (int m = 0; m < 4; ++m) {
        #pragma unroll
        for (int n = 0; n < 4; ++n) {
            const int col = n * 16 + l15;
            #pragma unroll
            for (int r = 0; r < 4; ++r) {
                obase[(size_t)(m * 16 + lk * 4 + r) * OUT_DIM + col] = acc[m][n][r];
            }
        }
    }
}

extern "C" void kernel_launch(void* const* d_in, const int* in_sizes, int n_in,
                              void* d_out, int out_size, void* d_ws, size_t ws_size,
                              hipStream_t stream) {
    const float* x    = (const float*)d_in[0];
    const int*   aids = (const int*)d_in[1];
    const float* w    = (const float*)d_in[2];
    float* out = (float*)d_out;
    const int nb = in_sizes[1];  // 8

    const size_t WT_BYTES = (size_t)NLORA * IN_DIM * OUT_DIM * 2;   // 256 MiB

    if (ws_size >= WT_BYTES) {
        unsigned short* wt = (unsigned short*)d_ws;

        prep_w<<<WBLKS, 256, 0, stream>>>(w, wt, aids, nb);

        const int nwg = nb * (S_DIM / BM) * (OUT_DIM / BN);  // 512
        gemm8p<<<nwg, 512, 0, stream>>>(x, wt, aids, out);
    } else {
        dim3 grid(OUT_DIM / TNf, S_DIM / TMf, nb);
        mlora_gemm<<<grid, 256, 0, stream>>>(x, aids, w, out);
    }
}

// Round 13
// 356.481 us; speedup vs baseline: 1.4604x; 1.4604x over previous
//
#include <hip/hip_runtime.h>
#include <hip/hip_bf16.h>

typedef __attribute__((ext_vector_type(8))) short short8;
typedef __attribute__((ext_vector_type(4))) float f32x4;

constexpr int S_DIM   = 1024;
constexpr int IN_DIM  = 4096;   // K
constexpr int OUT_DIM = 4096;   // N
constexpr int NLORA   = 8;

typedef __attribute__((address_space(3))) unsigned char lds_byte_t;
typedef const __attribute__((address_space(1))) unsigned char glb_byte_t;

__device__ __forceinline__ unsigned short f2bf(float a) {
    union { __hip_bfloat16 h; unsigned short u; } c;
    c.h = __float2bfloat16(a);
    return c.u;
}
__device__ __forceinline__ unsigned int bf2pk(float a, float b) {
    return (unsigned int)f2bf(a) | ((unsigned int)f2bf(b) << 16);
}

// ---- fused prep: w-transpose blocks + x-convert blocks in ONE launch --------
constexpr int WBLKS = NLORA * 64 * 64;   // 32768
constexpr int XBLKS = 2048;

__global__ __launch_bounds__(256)
void prep_all(const float* __restrict__ w, unsigned short* __restrict__ wt,
              const float* __restrict__ x, unsigned short* __restrict__ xb,
              const int* __restrict__ aids, int nb, int n8) {
    const int bid = blockIdx.x;
    const int tid = threadIdx.x;

    if (bid >= WBLKS) {
        const int xb0 = bid - WBLKS;
        const int stride = XBLKS * 256;
        for (int i = xb0 * 256 + tid; i < n8; i += stride) {
            const size_t o = (size_t)i * 8;
            f32x4 v0 = *reinterpret_cast<const f32x4*>(x + o);
            f32x4 v1 = *reinterpret_cast<const f32x4*>(x + o + 4);
            uint4 d;
            d.x = bf2pk(v0[0], v0[1]);
            d.y = bf2pk(v0[2], v0[3]);
            d.z = bf2pk(v1[0], v1[1]);
            d.w = bf2pk(v1[2], v1[3]);
            *reinterpret_cast<uint4*>(xb + o) = d;
        }
        return;
    }

    const int a = bid >> 12;
    bool used = false;
    for (int i = 0; i < nb; ++i) used |= (aids[i] == a);
    if (!used) return;

    const int r  = bid & 4095;
    const int n0 = (r & 63) * 64;
    const int k0 = (r >> 6) * 64;

    __shared__ __align__(16) unsigned short t[64][72];
    const float* wb = w + (size_t)a * IN_DIM * OUT_DIM;

    const int nl = (tid & 15) * 4;
    #pragma unroll
    for (int p = 0; p < 4; ++p) {
        const int kl = p * 16 + (tid >> 4);
        f32x4 v = *reinterpret_cast<const f32x4*>(wb + (size_t)(k0 + kl) * OUT_DIM + n0 + nl);
        t[nl + 0][kl] = f2bf(v[0]);
        t[nl + 1][kl] = f2bf(v[1]);
        t[nl + 2][kl] = f2bf(v[2]);
        t[nl + 3][kl] = f2bf(v[3]);
    }
    __syncthreads();
    unsigned short* wtb = wt + (size_t)a * IN_DIM * OUT_DIM;
    const int chunk = tid & 7;
    #pragma unroll
    for (int q = 0; q < 2; ++q) {
        const int row = q * 32 + (tid >> 3);
        uint4 d = *reinterpret_cast<const uint4*>(&t[row][chunk * 8]);
        *reinterpret_cast<uint4*>(wtb + (size_t)(n0 + row) * IN_DIM + k0 + chunk * 8) = d;
    }
}

// ---- main GEMM: 256x256, 4 phases/K-tile, PER-PHASE staggered staging -------
constexpr int BM = 256;
constexpr int BN = 256;
constexpr int BK = 64;
constexpr int NT = IN_DIM / BK;   // 64

__global__ __launch_bounds__(512, 2)
void gemm8p(const unsigned short* __restrict__ xb, const unsigned short* __restrict__ wt,
            const int* __restrict__ aids, float* __restrict__ out) {
    __shared__ __align__(16) unsigned char lds[2][65536];

    // T1 XCD swizzle: 512 wgs, 64/XCD = exactly one batch per XCD
    const int bid = blockIdx.x;
    const int swz = (bid & 7) * 64 + (bid >> 3);
    const int bz  = swz >> 6;
    const int rem = swz & 63;
    const int by  = rem >> 4;
    const int bx  = rem & 15;

    const int tid  = threadIdx.x;
    const int lane = tid & 63;
    const int wid  = tid >> 6;
    const int bm0  = by * BM;
    const int bn0  = bx * BN;
    const int aid  = aids[bz];

    const unsigned short* Ab = xb + ((size_t)bz * S_DIM + bm0) * IN_DIM;
    const unsigned short* Bb = wt + (size_t)aid * IN_DIM * OUT_DIM + (size_t)bn0 * IN_DIM;

    const int wr  = (wid >> 2) * 128;
    const int wc  = (wid & 3) * 64;
    const int l15 = lane & 15;
    const int lk  = lane >> 4;

    // staging: chunk = 8 rows x 128B, linear LDS dest, source k pre-swizzled
    // so ds_read with byte ^ ((row&7)<<4) is conflict-free (verified r3-r11).
    const int rl   = lane >> 3;
    const int ksrc = ((lane & 7) ^ rl) << 3;

    f32x4 acc[8][4] = {};

    // A group g (g=mh): rows {g*64..+63} u {128+g*64..+63} = chunks c*16+g*8+wid
    // == exactly the rows ALL waves read at readA(mh=g)  [proven r8/r9]
    auto stageA = [&](int buf, int k0, int g) {
        #pragma unroll
        for (int c = 0; c < 2; ++c) {
            const int chunk = c * 16 + g * 8 + wid;
            const int row   = chunk * 8 + rl;
            __builtin_amdgcn_global_load_lds(
                (glb_byte_t*)(Ab + (size_t)row * IN_DIM + k0 + ksrc),
                (lds_byte_t*)(&lds[buf][chunk * 1024]), 16, 0, 0);
        }
    };
    // B group g (g=np): rows {w*64+g*32..+31} = chunks (wid>>1)*8+g*4+(wid&1)*2+c
    // == exactly the rows ALL waves read at readB(np=g)
    auto stageB = [&](int buf, int k0, int g) {
        #pragma unroll
        for (int c = 0; c < 2; ++c) {
            const int chunk = (wid >> 1) * 8 + g * 4 + (wid & 1) * 2 + c;
            const int row   = chunk * 8 + rl;
            __builtin_amdgcn_global_load_lds(
                (glb_byte_t*)(Bb + (size_t)row * IN_DIM + k0 + ksrc),
                (lds_byte_t*)(&lds[buf][32768 + chunk * 1024]), 16, 0, 0);
        }
    };

    auto readA = [&](int buf, int mh, short8 (&af)[4][2]) {
        #pragma unroll
        for (int i = 0; i < 4; ++i) {
            const int row = wr + mh * 64 + i * 16 + l15;
            #pragma unroll
            for (int kc = 0; kc < 2; ++kc) {
                const int kb = kc * 64 + lk * 16;
                af[i][kc] = *reinterpret_cast<const short8*>(
                    &lds[buf][row * 128 + (kb ^ ((row & 7) << 4))]);
            }
        }
    };
    auto readB = [&](int buf, int np, short8 (&bf)[2][2]) {
        #pragma unroll
        for (int nn = 0; nn < 2; ++nn) {
            const int row = wc + np * 32 + nn * 16 + l15;
            #pragma unroll
            for (int kc = 0; kc < 2; ++kc) {
                const int kb = kc * 64 + lk * 16;
                bf[nn][kc] = *reinterpret_cast<const short8*>(
                    &lds[buf][32768 + row * 128 + (kb ^ ((row & 7) << 4))]);
            }
        }
    };

    auto qmfma = [&](short8 (&af)[4][2], short8 (&bf)[2][2], int mh, int np) {
        __builtin_amdgcn_s_setprio(1);
        #pragma unroll
        for (int i = 0; i < 4; ++i)
            #pragma unroll
            for (int nn = 0; nn < 2; ++nn)
                #pragma unroll
                for (int kc = 0; kc < 2; ++kc)
                    acc[mh * 4 + i][np * 2 + nn] = __builtin_amdgcn_mfma_f32_16x16x32_bf16(
                        af[i][kc], bf[nn][kc], acc[mh * 4 + i][np * 2 + nn], 0, 0, 0);
        __builtin_amdgcn_s_setprio(0);
    };

    // prologue: tile0 -> buf0 (8 loads), tile1 -> buf1 (8); vmcnt(8) drains tile0
    stageA(0, 0, 0); stageA(0, 0, 1); stageB(0, 0, 0); stageB(0, 0, 1);
    stageA(1, BK, 0); stageA(1, BK, 1); stageB(1, BK, 0); stageB(1, BK, 1);
    asm volatile("s_waitcnt vmcnt(8)" ::: "memory");
    __builtin_amdgcn_sched_barrier(0);
    __builtin_amdgcn_s_barrier();

    short8 a0[4][2], a1[4][2], b0[2][2], b1[2][2];

    #pragma unroll 1
    for (int j = 0; j < NT; ++j) {
        const int rb = j & 1;                 // read buf; tile j+2 lands here too
        const int k2 = (j + 2) * BK;
        const bool pre = (j < NT - 2);

        // ---- ph0: (mh0,np0); no stage (nothing of tile j retired yet) ----
        readA(rb, 0, a0);
        readB(rb, 0, b0);
        __builtin_amdgcn_s_barrier();
        qmfma(a0, b0, 0, 0);
        __builtin_amdgcn_s_barrier();

        // ---- ph1: (mh0,np1); stage B-np0 (retired at ph0-end barrier) ----
        readB(rb, 1, b1);
        if (pre) stageB(rb, k2, 0);
        __builtin_amdgcn_sched_barrier(0);
        __builtin_amdgcn_s_barrier();
        qmfma(a0, b1, 0, 1);
        __builtin_amdgcn_s_barrier();

        // ---- ph2: (mh1,np1); stage A-mh0 (retired at ph0-end barrier) ----
        readA(rb, 1, a1);
        if (pre) stageA(rb, k2, 0);
        __builtin_amdgcn_sched_barrier(0);
        __builtin_amdgcn_s_barrier();
        qmfma(a1, b1, 1, 1);
        __builtin_amdgcn_s_barrier();

        // ---- ph3: (mh1,np0); stage B-np1 (ph1-end) + A-mh1 (ph2-end) ----
        if (pre) {
            stageB(rb, k2, 1);
            stageA(rb, k2, 1);
            asm volatile("s_waitcnt vmcnt(8)" ::: "memory");  // tile j+1 landed
        } else if (j == NT - 2) {
            asm volatile("s_waitcnt vmcnt(0)" ::: "memory");  // drain last tile
        }
        __builtin_amdgcn_sched_barrier(0);
        __builtin_amdgcn_s_barrier();
        qmfma(a1, b0, 1, 0);
        __builtin_amdgcn_s_barrier();
    }

    // ---- epilogue: D layout col=lane&15, row=(lane>>4)*4+reg ----
    float* obase = out + ((size_t)bz * S_DIM + bm0 + wr) * OUT_DIM + bn0 + wc;
    #pragma unroll
    for (int m = 0; m < 8; ++m) {
        #pragma unroll
        for (int n = 0; n < 4; ++n) {
            const int col = n * 16 + l15;
            #pragma unroll
            for (int r = 0; r < 4; ++r) {
                obase[(size_t)(m * 16 + lk * 4 + r) * OUT_DIM + col] = acc[m][n][r];
            }
        }
    }
}

// ---- fallback: round-2 fused kernel (passes @1316us, needs no ws) -----------
constexpr int TMf = 128, TNf = 128, TKf = 64;
__global__ __launch_bounds__(256, 2)
void mlora_gemm(const float* __restrict__ x, const int* __restrict__ aids,
                const float* __restrict__ w, float* __restrict__ out) {
    __shared__ __align__(16) unsigned char Asf[TMf * TKf * 2];
    __shared__ __align__(16) unsigned char Bsf[TNf * TKf * 2];

    const int tid  = threadIdx.x;
    const int lane = tid & 63;
    const int wid  = tid >> 6;
    const int bn0  = blockIdx.x * TNf;
    const int bm0  = blockIdx.y * TMf;
    const int bb   = blockIdx.z;
    const int aid  = aids[bb];

    const float* Abase = x + ((size_t)bb * S_DIM + bm0) * IN_DIM;
    const float* Bbase = w + (size_t)aid * IN_DIM * OUT_DIM + bn0;

    const int wr = (wid >> 1) * 64;
    const int wc = (wid & 1) * 64;

    f32x4 acc[4][4] = {};

    const int a_row4 = tid >> 4;
    const int a_k    = (tid & 15) * 4;
    const int b_n  = tid & 127;
    const int b_k0 = (tid >> 7) * 8;
    const int l15 = lane & 15;
    const int lk  = lane >> 4;

    for (int k0 = 0; k0 < IN_DIM; k0 += TKf) {
        #pragma unroll
        for (int p = 0; p < 8; ++p) {
            const int row = p * 16 + a_row4;
            f32x4 v = *reinterpret_cast<const f32x4*>(Abase + (size_t)row * IN_DIM + (k0 + a_k));
            uint2 d;
            d.x = bf2pk(v[0], v[1]);
            d.y = bf2pk(v[2], v[3]);
            const int off = row * (TKf * 2) + ((a_k * 2) ^ ((row & 7) << 4));
            *reinterpret_cast<uint2*>(&Asf[off]) = d;
        }
        {
            const float* bp = Bbase + (size_t)(k0 + b_k0) * OUT_DIM + b_n;
            #pragma unroll
            for (int g = 0; g < 4; ++g) {
                float f0 = bp[(size_t)(g * 16 + 0) * OUT_DIM];
                float f1 = bp[(size_t)(g * 16 + 1) * OUT_DIM];
                float f2 = bp[(size_t)(g * 16 + 2) * OUT_DIM];
                float f3 = bp[(size_t)(g * 16 + 3) * OUT_DIM];
                float f4 = bp[(size_t)(g * 16 + 4) * OUT_DIM];
                float f5 = bp[(size_t)(g * 16 + 5) * OUT_DIM];
                float f6 = bp[(size_t)(g * 16 + 6) * OUT_DIM];
                float f7 = bp[(size_t)(g * 16 + 7) * OUT_DIM];
                uint4 d;
                d.x = bf2pk(f0, f1);
                d.y = bf2pk(f2, f3);
                d.z = bf2pk(f4, f5);
                d.w = bf2pk(f6, f7);
                const int ks = b_k0 + g * 16;
                const int off = b_n * (TKf * 2) + ((ks * 2) ^ ((b_n & 7) << 4));
                *reinterpret_cast<uint4*>(&Bsf[off]) = d;
            }
        }
        __syncthreads();
        #pragma unroll
        for (int kc = 0; kc < 2; ++kc) {
            const int kbyte = kc * 64 + lk * 16;
            short8 af[4], bfr[4];
            #pragma unroll
            for (int m = 0; m < 4; ++m) {
                const int row = wr + m * 16 + l15;
                af[m] = *reinterpret_cast<const short8*>(&Asf[row * (TKf * 2) + (kbyte ^ ((row & 7) << 4))]);
            }
            #pragma unroll
            for (int n = 0; n < 4; ++n) {
                const int row = wc + n * 16 + l15;
                bfr[n] = *reinterpret_cast<const short8*>(&Bsf[row * (TKf * 2) + (kbyte ^ ((row & 7) << 4))]);
            }
            #pragma unroll
            for (int m = 0; m < 4; ++m) {
                #pragma unroll
                for (int n = 0; n < 4; ++n) {
                    acc[m][n] = __builtin_amdgcn_mfma_f32_16x16x32_bf16(af[m], bfr[n], acc[m][n], 0, 0, 0);
                }
            }
        }
        __syncthreads();
    }

    float* obase = out + ((size_t)bb * S_DIM + bm0 + wr) * OUT_DIM + bn0 + wc;
    #pragma unroll
    for (int m = 0; m < 4; ++m) {
        #pragma unroll
        for (int n = 0; n < 4; ++n) {
            const int col = n * 16 + l15;
            #pragma unroll
            for (int r = 0; r < 4; ++r) {
                obase[(size_t)(m * 16 + lk * 4 + r) * OUT_DIM + col] = acc[m][n][r];
            }
        }
    }
}

extern "C" void kernel_launch(void* const* d_in, const int* in_sizes, int n_in,
                              void* d_out, int out_size, void* d_ws, size_t ws_size,
                              hipStream_t stream) {
    const float* x    = (const float*)d_in[0];
    const int*   aids = (const int*)d_in[1];
    const float* w    = (const float*)d_in[2];
    float* out = (float*)d_out;
    const int nb = in_sizes[1];  // 8

    const size_t WT_BYTES = (size_t)NLORA * IN_DIM * OUT_DIM * 2;   // 256 MiB
    const size_t XB_BYTES = (size_t)nb * S_DIM * IN_DIM * 2;        // 64 MiB

    if (ws_size >= WT_BYTES + XB_BYTES) {
        unsigned short* wt = (unsigned short*)d_ws;
        unsigned short* xbuf = (unsigned short*)((char*)d_ws + WT_BYTES);

        const int n8 = nb * S_DIM * IN_DIM / 8;
        prep_all<<<WBLKS + XBLKS, 256, 0, stream>>>(w, wt, x, xbuf, aids, nb, n8);

        const int nwg = nb * (S_DIM / BM) * (OUT_DIM / BN);  // 512
        gemm8p<<<nwg, 512, 0, stream>>>(xbuf, wt, aids, out);
    } else {
        dim3 grid(OUT_DIM / TNf, S_DIM / TMf, nb);
        mlora_gemm<<<grid, 256, 0, stream>>>(x, aids, w, out);
    }
}

// Round 14
// 356.227 us; speedup vs baseline: 1.4614x; 1.0007x over previous
//
#include <hip/hip_runtime.h>
#include <hip/hip_bf16.h>

typedef __attribute__((ext_vector_type(8))) short short8;
typedef __attribute__((ext_vector_type(4))) float f32x4;

constexpr int S_DIM   = 1024;
constexpr int IN_DIM  = 4096;   // K
constexpr int OUT_DIM = 4096;   // N
constexpr int NLORA   = 8;

typedef __attribute__((address_space(3))) unsigned char lds_byte_t;
typedef const __attribute__((address_space(1))) unsigned char glb_byte_t;

__device__ __forceinline__ unsigned short f2bf(float a) {
    union { __hip_bfloat16 h; unsigned short u; } c;
    c.h = __float2bfloat16(a);
    return c.u;
}
__device__ __forceinline__ unsigned int bf2pk(float a, float b) {
    return (unsigned int)f2bf(a) | ((unsigned int)f2bf(b) << 16);
}

// ---- fused prep: w-transpose blocks + x-convert blocks in ONE launch --------
constexpr int WBLKS = NLORA * 64 * 64;   // 32768
constexpr int XBLKS = 2048;

__global__ __launch_bounds__(256)
void prep_all(const float* __restrict__ w, unsigned short* __restrict__ wt,
              const float* __restrict__ x, unsigned short* __restrict__ xb,
              const int* __restrict__ aids, int nb, int n8) {
    const int bid = blockIdx.x;
    const int tid = threadIdx.x;

    if (bid >= WBLKS) {
        const int xb0 = bid - WBLKS;
        const int stride = XBLKS * 256;
        for (int i = xb0 * 256 + tid; i < n8; i += stride) {
            const size_t o = (size_t)i * 8;
            f32x4 v0 = *reinterpret_cast<const f32x4*>(x + o);
            f32x4 v1 = *reinterpret_cast<const f32x4*>(x + o + 4);
            uint4 d;
            d.x = bf2pk(v0[0], v0[1]);
            d.y = bf2pk(v0[2], v0[3]);
            d.z = bf2pk(v1[0], v1[1]);
            d.w = bf2pk(v1[2], v1[3]);
            *reinterpret_cast<uint4*>(xb + o) = d;
        }
        return;
    }

    const int a = bid >> 12;
    bool used = false;
    for (int i = 0; i < nb; ++i) used |= (aids[i] == a);
    if (!used) return;

    const int r  = bid & 4095;
    const int n0 = (r & 63) * 64;
    const int k0 = (r >> 6) * 64;

    // stride 66 u16 = 132 B = 33 u32-banks: u32 bank = (n + k2) mod 32.
    // phase-1 u16 writes ~2-way (free), phase-2 u32 reads ~1-2-way.
    // (old [64][72]: writes 8-16-way, b128 reads 8-way = 2.94x LDS cost)
    __shared__ __align__(16) unsigned short t[64][66];
    const float* wb = w + (size_t)a * IN_DIM * OUT_DIM;

    const int nl = (tid & 15) * 4;
    #pragma unroll
    for (int p = 0; p < 4; ++p) {
        const int kl = p * 16 + (tid >> 4);
        f32x4 v = *reinterpret_cast<const f32x4*>(wb + (size_t)(k0 + kl) * OUT_DIM + n0 + nl);
        t[nl + 0][kl] = f2bf(v[0]);
        t[nl + 1][kl] = f2bf(v[1]);
        t[nl + 2][kl] = f2bf(v[2]);
        t[nl + 3][kl] = f2bf(v[3]);
    }
    __syncthreads();
    unsigned short* wtb = wt + (size_t)a * IN_DIM * OUT_DIM;
    const int chunk = tid & 7;
    #pragma unroll
    for (int q = 0; q < 2; ++q) {
        const int row = q * 32 + (tid >> 3);
        // 4 scalar u32 reads (4B-aligned; 132B rows are not 16B-aligned)
        const unsigned int* rp = reinterpret_cast<const unsigned int*>(&t[row][0]);
        uint4 d;
        d.x = rp[chunk * 4 + 0];
        d.y = rp[chunk * 4 + 1];
        d.z = rp[chunk * 4 + 2];
        d.w = rp[chunk * 4 + 3];
        *reinterpret_cast<uint4*>(wtb + (size_t)(n0 + row) * IN_DIM + k0 + chunk * 8) = d;
    }
}

// ---- main GEMM: 256x256, 4 phases/K-tile, PER-PHASE staggered staging -------
// (byte-identical to the banked round-11/13 kernel, 221 us / 1244 TF)
constexpr int BM = 256;
constexpr int BN = 256;
constexpr int BK = 64;
constexpr int NT = IN_DIM / BK;   // 64

__global__ __launch_bounds__(512, 2)
void gemm8p(const unsigned short* __restrict__ xb, const unsigned short* __restrict__ wt,
            const int* __restrict__ aids, float* __restrict__ out) {
    __shared__ __align__(16) unsigned char lds[2][65536];

    // T1 XCD swizzle: 512 wgs, 64/XCD = exactly one batch per XCD
    const int bid = blockIdx.x;
    const int swz = (bid & 7) * 64 + (bid >> 3);
    const int bz  = swz >> 6;
    const int rem = swz & 63;
    const int by  = rem >> 4;
    const int bx  = rem & 15;

    const int tid  = threadIdx.x;
    const int lane = tid & 63;
    const int wid  = tid >> 6;
    const int bm0  = by * BM;
    const int bn0  = bx * BN;
    const int aid  = aids[bz];

    const unsigned short* Ab = xb + ((size_t)bz * S_DIM + bm0) * IN_DIM;
    const unsigned short* Bb = wt + (size_t)aid * IN_DIM * OUT_DIM + (size_t)bn0 * IN_DIM;

    const int wr  = (wid >> 2) * 128;
    const int wc  = (wid & 3) * 64;
    const int l15 = lane & 15;
    const int lk  = lane >> 4;

    // staging: chunk = 8 rows x 128B, linear LDS dest, source k pre-swizzled
    // so ds_read with byte ^ ((row&7)<<4) is conflict-free (verified r3-r13).
    const int rl   = lane >> 3;
    const int ksrc = ((lane & 7) ^ rl) << 3;

    f32x4 acc[8][4] = {};

    // A group g (g=mh): rows {g*64..+63} u {128+g*64..+63} = chunks c*16+g*8+wid
    // == exactly the rows ALL waves read at readA(mh=g)  [proven r8/r9]
    auto stageA = [&](int buf, int k0, int g) {
        #pragma unroll
        for (int c = 0; c < 2; ++c) {
            const int chunk = c * 16 + g * 8 + wid;
            const int row   = chunk * 8 + rl;
            __builtin_amdgcn_global_load_lds(
                (glb_byte_t*)(Ab + (size_t)row * IN_DIM + k0 + ksrc),
                (lds_byte_t*)(&lds[buf][chunk * 1024]), 16, 0, 0);
        }
    };
    // B group g (g=np): rows {w*64+g*32..+31} = chunks (wid>>1)*8+g*4+(wid&1)*2+c
    // == exactly the rows ALL waves read at readB(np=g)
    auto stageB = [&](int buf, int k0, int g) {
        #pragma unroll
        for (int c = 0; c < 2; ++c) {
            const int chunk = (wid >> 1) * 8 + g * 4 + (wid & 1) * 2 + c;
            const int row   = chunk * 8 + rl;
            __builtin_amdgcn_global_load_lds(
                (glb_byte_t*)(Bb + (size_t)row * IN_DIM + k0 + ksrc),
                (lds_byte_t*)(&lds[buf][32768 + chunk * 1024]), 16, 0, 0);
        }
    };

    auto readA = [&](int buf, int mh, short8 (&af)[4][2]) {
        #pragma unroll
        for (int i = 0; i < 4; ++i) {
            const int row = wr + mh * 64 + i * 16 + l15;
            #pragma unroll
            for (int kc = 0; kc < 2; ++kc) {
                const int kb = kc * 64 + lk * 16;
                af[i][kc] = *reinterpret_cast<const short8*>(
                    &lds[buf][row * 128 + (kb ^ ((row & 7) << 4))]);
            }
        }
    };
    auto readB = [&](int buf, int np, short8 (&bf)[2][2]) {
        #pragma unroll
        for (int nn = 0; nn < 2; ++nn) {
            const int row = wc + np * 32 + nn * 16 + l15;
            #pragma unroll
            for (int kc = 0; kc < 2; ++kc) {
                const int kb = kc * 64 + lk * 16;
                bf[nn][kc] = *reinterpret_cast<const short8*>(
                    &lds[buf][32768 + row * 128 + (kb ^ ((row & 7) << 4))]);
            }
        }
    };

    auto qmfma = [&](short8 (&af)[4][2], short8 (&bf)[2][2], int mh, int np) {
        __builtin_amdgcn_s_setprio(1);
        #pragma unroll
        for (int i = 0; i < 4; ++i)
            #pragma unroll
            for (int nn = 0; nn < 2; ++nn)
                #pragma unroll
                for (int kc = 0; kc < 2; ++kc)
                    acc[mh * 4 + i][np * 2 + nn] = __builtin_amdgcn_mfma_f32_16x16x32_bf16(
                        af[i][kc], bf[nn][kc], acc[mh * 4 + i][np * 2 + nn], 0, 0, 0);
        __builtin_amdgcn_s_setprio(0);
    };

    // prologue: tile0 -> buf0 (8 loads), tile1 -> buf1 (8); vmcnt(8) drains tile0
    stageA(0, 0, 0); stageA(0, 0, 1); stageB(0, 0, 0); stageB(0, 0, 1);
    stageA(1, BK, 0); stageA(1, BK, 1); stageB(1, BK, 0); stageB(1, BK, 1);
    asm volatile("s_waitcnt vmcnt(8)" ::: "memory");
    __builtin_amdgcn_sched_barrier(0);
    __builtin_amdgcn_s_barrier();

    short8 a0[4][2], a1[4][2], b0[2][2], b1[2][2];

    #pragma unroll 1
    for (int j = 0; j < NT; ++j) {
        const int rb = j & 1;                 // read buf; tile j+2 lands here too
        const int k2 = (j + 2) * BK;
        const bool pre = (j < NT - 2);

        // ---- ph0: (mh0,np0); no stage (nothing of tile j retired yet) ----
        readA(rb, 0, a0);
        readB(rb, 0, b0);
        __builtin_amdgcn_s_barrier();
        qmfma(a0, b0, 0, 0);
        __builtin_amdgcn_s_barrier();

        // ---- ph1: (mh0,np1); stage B-np0 (retired at ph0-end barrier) ----
        readB(rb, 1, b1);
        if (pre) stageB(rb, k2, 0);
        __builtin_amdgcn_sched_barrier(0);
        __builtin_amdgcn_s_barrier();
        qmfma(a0, b1, 0, 1);
        __builtin_amdgcn_s_barrier();

        // ---- ph2: (mh1,np1); stage A-mh0 (retired at ph0-end barrier) ----
        readA(rb, 1, a1);
        if (pre) stageA(rb, k2, 0);
        __builtin_amdgcn_sched_barrier(0);
        __builtin_amdgcn_s_barrier();
        qmfma(a1, b1, 1, 1);
        __builtin_amdgcn_s_barrier();

        // ---- ph3: (mh1,np0); stage B-np1 (ph1-end) + A-mh1 (ph2-end) ----
        if (pre) {
            stageB(rb, k2, 1);
            stageA(rb, k2, 1);
            asm volatile("s_waitcnt vmcnt(8)" ::: "memory");  // tile j+1 landed
        } else if (j == NT - 2) {
            asm volatile("s_waitcnt vmcnt(0)" ::: "memory");  // drain last tile
        }
        __builtin_amdgcn_sched_barrier(0);
        __builtin_amdgcn_s_barrier();
        qmfma(a1, b0, 1, 0);
        __builtin_amdgcn_s_barrier();
    }

    // ---- epilogue: D layout col=lane&15, row=(lane>>4)*4+reg ----
    float* obase = out + ((size_t)bz * S_DIM + bm0 + wr) * OUT_DIM + bn0 + wc;
    #pragma unroll
    for (int m = 0; m < 8; ++m) {
        #pragma unroll
        for (int n = 0; n < 4; ++n) {
            const int col = n * 16 + l15;
            #pragma unroll
            for (int r = 0; r < 4; ++r) {
                obase[(size_t)(m * 16 + lk * 4 + r) * OUT_DIM + col] = acc[m][n][r];
            }
        }
    }
}

// ---- fallback: round-2 fused kernel (passes @1316us, needs no ws) -----------
constexpr int TMf = 128, TNf = 128, TKf = 64;
__global__ __launch_bounds__(256, 2)
void mlora_gemm(const float* __restrict__ x, const int* __restrict__ aids,
                const float* __restrict__ w, float* __restrict__ out) {
    __shared__ __align__(16) unsigned char Asf[TMf * TKf * 2];
    __shared__ __align__(16) unsigned char Bsf[TNf * TKf * 2];

    const int tid  = threadIdx.x;
    const int lane = tid & 63;
    const int wid  = tid >> 6;
    const int bn0  = blockIdx.x * TNf;
    const int bm0  = blockIdx.y * TMf;
    const int bb   = blockIdx.z;
    const int aid  = aids[bb];

    const float* Abase = x + ((size_t)bb * S_DIM + bm0) * IN_DIM;
    const float* Bbase = w + (size_t)aid * IN_DIM * OUT_DIM + bn0;

    const int wr = (wid >> 1) * 64;
    const int wc = (wid & 1) * 64;

    f32x4 acc[4][4] = {};

    const int a_row4 = tid >> 4;
    const int a_k    = (tid & 15) * 4;
    const int b_n  = tid & 127;
    const int b_k0 = (tid >> 7) * 8;
    const int l15 = lane & 15;
    const int lk  = lane >> 4;

    for (int k0 = 0; k0 < IN_DIM; k0 += TKf) {
        #pragma unroll
        for (int p = 0; p < 8; ++p) {
            const int row = p * 16 + a_row4;
            f32x4 v = *reinterpret_cast<const f32x4*>(Abase + (size_t)row * IN_DIM + (k0 + a_k));
            uint2 d;
            d.x = bf2pk(v[0], v[1]);
            d.y = bf2pk(v[2], v[3]);
            const int off = row * (TKf * 2) + ((a_k * 2) ^ ((row & 7) << 4));
            *reinterpret_cast<uint2*>(&Asf[off]) = d;
        }
        {
            const float* bp = Bbase + (size_t)(k0 + b_k0) * OUT_DIM + b_n;
            #pragma unroll
            for (int g = 0; g < 4; ++g) {
                float f0 = bp[(size_t)(g * 16 + 0) * OUT_DIM];
                float f1 = bp[(size_t)(g * 16 + 1) * OUT_DIM];
                float f2 = bp[(size_t)(g * 16 + 2) * OUT_DIM];
                float f3 = bp[(size_t)(g * 16 + 3) * OUT_DIM];
                float f4 = bp[(size_t)(g * 16 + 4) * OUT_DIM];
                float f5 = bp[(size_t)(g * 16 + 5) * OUT_DIM];
                float f6 = bp[(size_t)(g * 16 + 6) * OUT_DIM];
                float f7 = bp[(size_t)(g * 16 + 7) * OUT_DIM];
                uint4 d;
                d.x = bf2pk(f0, f1);
                d.y = bf2pk(f2, f3);
                d.z = bf2pk(f4, f5);
                d.w = bf2pk(f6, f7);
                const int ks = b_k0 + g * 16;
                const int off = b_n * (TKf * 2) + ((ks * 2) ^ ((b_n & 7) << 4));
                *reinterpret_cast<uint4*>(&Bsf[off]) = d;
            }
        }
        __syncthreads();
        #pragma unroll
        for (int kc = 0; kc < 2; ++kc) {
            const int kbyte = kc * 64 + lk * 16;
            short8 af[4], bfr[4];
            #pragma unroll
            for (int m = 0; m < 4; ++m) {
                const int row = wr + m * 16 + l15;
                af[m] = *reinterpret_cast<const short8*>(&Asf[row * (TKf * 2) + (kbyte ^ ((row & 7) << 4))]);
            }
            #pragma unroll
            for (int n = 0; n < 4; ++n) {
                const int row = wc + n * 16 + l15;
                bfr[n] = *reinterpret_cast<const short8*>(&Bsf[row * (TKf * 2) + (kbyte ^ ((row & 7) << 4))]);
            }
            #pragma unroll
            for (int m = 0; m < 4; ++m) {
                #pragma unroll
                for (int n = 0; n < 4; ++n) {
                    acc[m][n] = __builtin_amdgcn_mfma_f32_16x16x32_bf16(af[m], bfr[n], acc[m][n], 0, 0, 0);
                }
            }
        }
        __syncthreads();
    }

    float* obase = out + ((size_t)bb * S_DIM + bm0 + wr) * OUT_DIM + bn0 + wc;
    #pragma unroll
    for (int m = 0; m < 4; ++m) {
        #pragma unroll
        for (int n = 0; n < 4; ++n) {
            const int col = n * 16 + l15;
            #pragma unroll
            for (int r = 0; r < 4; ++r) {
                obase[(size_t)(m * 16 + lk * 4 + r) * OUT_DIM + col] = acc[m][n][r];
            }
        }
    }
}

extern "C" void kernel_launch(void* const* d_in, const int* in_sizes, int n_in,
                              void* d_out, int out_size, void* d_ws, size_t ws_size,
                              hipStream_t stream) {
    const float* x    = (const float*)d_in[0];
    const int*   aids = (const int*)d_in[1];
    const float* w    = (const float*)d_in[2];
    float* out = (float*)d_out;
    const int nb = in_sizes[1];  // 8

    const size_t WT_BYTES = (size_t)NLORA * IN_DIM * OUT_DIM * 2;   // 256 MiB
    const size_t XB_BYTES = (size_t)nb * S_DIM * IN_DIM * 2;        // 64 MiB

    if (ws_size >= WT_BYTES + XB_BYTES) {
        unsigned short* wt = (unsigned short*)d_ws;
        unsigned short* xbuf = (unsigned short*)((char*)d_ws + WT_BYTES);

        const int n8 = nb * S_DIM * IN_DIM / 8;
        prep_all<<<WBLKS + XBLKS, 256, 0, stream>>>(w, wt, x, xbuf, aids, nb, n8);

        const int nwg = nb * (S_DIM / BM) * (OUT_DIM / BN);  // 512
        gemm8p<<<nwg, 512, 0, stream>>>(xbuf, wt, aids, out);
    } else {
        dim3 grid(OUT_DIM / TNf, S_DIM / TMf, nb);
        mlora_gemm<<<grid, 256, 0, stream>>>(x, aids, w, out);
    }
}